// Round 1
// baseline (6074.028 us; speedup 1.0000x reference)
//
#include <hip/hip_runtime.h>
#include <math.h>

#define HDIM 128

// -------- Edge aggregation: m[dst] += feat[e] * h[src], 32 threads/edge ------
__global__ __launch_bounds__(256) void edge_agg_kernel(
    const float* __restrict__ h, const float* __restrict__ feat,
    const int* __restrict__ src, const int* __restrict__ dst,
    float* __restrict__ m, int n_edges)
{
    long long tid = (long long)blockIdx.x * 256 + threadIdx.x;
    int e = (int)(tid >> 5);
    if (e >= n_edges) return;
    int q = (int)(tid & 31);                 // 4-float chunk 0..31
    float f = feat[e];
    size_t s = (size_t)src[e] * HDIM;
    size_t d = (size_t)dst[e] * HDIM;
    float4 v = reinterpret_cast<const float4*>(h + s)[q];
    float* mp = m + d + (size_t)q * 4;
    unsafeAtomicAdd(mp + 0, f * v.x);
    unsafeAtomicAdd(mp + 1, f * v.y);
    unsafeAtomicAdd(mp + 2, f * v.z);
    unsafeAtomicAdd(mp + 3, f * v.w);
}

// -------- Fused GEMM [N,256]x[256,128] + bias + exact GELU + residual --------
// W staged in LDS (128 KB). 256 threads: 2 nodes per iteration, thread half
// (0/1) picks the node, c = tid & 127 picks the output column.
__global__ __launch_bounds__(256) void gemm_gelu_res_kernel(
    const float* __restrict__ mct, const float* __restrict__ mcb,
    const float* __restrict__ W, const float* __restrict__ bias,
    const float* __restrict__ h_in, float* __restrict__ h_out, int n_nodes)
{
    __shared__ float Wl[256 * HDIM];      // 128 KB
    __shared__ float trow[2][2 * HDIM];   // 2 nodes x 256
    for (int i = threadIdx.x; i < 256 * HDIM; i += 256)
        Wl[i] = W[i];
    const int c = threadIdx.x & 127;
    const int half = threadIdx.x >> 7;
    const float bc = bias[c];
    __syncthreads();

    int npairs = (n_nodes + 1) >> 1;
    for (int pair = blockIdx.x; pair < npairs; pair += gridDim.x) {
        __syncthreads();   // protect trow from previous iteration's readers
        // stage t = concat(mct_row, mcb_row) for the 2 nodes of this pair
        for (int j = threadIdx.x; j < 512; j += 256) {
            int nn = j >> 8;           // node within pair
            int k  = j & 255;          // column of t
            long long node = (long long)pair * 2 + nn;
            float val = 0.0f;
            if (node < n_nodes)
                val = (k < HDIM) ? mct[node * HDIM + k]
                                 : mcb[node * HDIM + (k - HDIM)];
            trow[nn][k] = val;
        }
        __syncthreads();
        long long n = (long long)pair * 2 + half;
        if (n < n_nodes) {
            const float* tr = trow[half];
            float acc = bc;
            #pragma unroll 8
            for (int k = 0; k < 256; ++k)
                acc = fmaf(tr[k], Wl[k * HDIM + c], acc);
            float g = 0.5f * acc * (1.0f + erff(acc * 0.70710678118654752f));
            h_out[n * HDIM + c] = h_in[n * HDIM + c] + g;
        }
    }
}

extern "C" void kernel_launch(void* const* d_in, const int* in_sizes, int n_in,
                              void* d_out, int out_size, void* d_ws, size_t ws_size,
                              hipStream_t stream)
{
    const float* h0      = (const float*)d_in[0];
    const float* feat_ct = (const float*)d_in[1];
    const float* feat_cb = (const float*)d_in[2];
    const int*   src_ct  = (const int*)d_in[3];
    const int*   dst_ct  = (const int*)d_in[4];
    const int*   src_cb  = (const int*)d_in[5];
    const int*   dst_cb  = (const int*)d_in[6];
    const float* W0      = (const float*)d_in[7];
    const float* b0      = (const float*)d_in[8];
    const float* W1      = (const float*)d_in[9];
    const float* b1      = (const float*)d_in[10];

    const int n_nodes    = in_sizes[0] / HDIM;
    const int n_edges_ct = in_sizes[3];
    const int n_edges_cb = in_sizes[5];
    float* out = (float*)d_out;

    float* mct = (float*)d_ws;
    float* mcb = mct + (size_t)n_nodes * HDIM;
    const size_t mbytes = (size_t)n_nodes * HDIM * sizeof(float) * 2;

    const int agg_blocks_ct = (int)(((long long)n_edges_ct * 32 + 255) / 256);
    const int agg_blocks_cb = (int)(((long long)n_edges_cb * 32 + 255) / 256);
    const int gemm_blocks = 256;   // 1 block/CU (128KB LDS), grid-stride pairs

    const float* hcur = h0;
    for (int layer = 0; layer < 2; ++layer) {
        hipMemsetAsync(d_ws, 0, mbytes, stream);
        edge_agg_kernel<<<agg_blocks_ct, 256, 0, stream>>>(
            hcur, feat_ct, src_ct, dst_ct, mct, n_edges_ct);
        edge_agg_kernel<<<agg_blocks_cb, 256, 0, stream>>>(
            hcur, feat_cb, src_cb, dst_cb, mcb, n_edges_cb);
        const float* W = layer ? W1 : W0;
        const float* b = layer ? b1 : b0;
        gemm_gelu_res_kernel<<<gemm_blocks, 256, 0, stream>>>(
            mct, mcb, W, b, hcur, out, n_nodes);
        hcur = out;
    }
}

// Round 2
// 1052.520 us; speedup vs baseline: 5.7709x; 5.7709x over previous
//
#include <hip/hip_runtime.h>
#include <math.h>

#define HDIM 128

// ---------------- CSR build: histogram ----------------
__global__ __launch_bounds__(256) void hist_kernel(
    const int* __restrict__ dst, int* __restrict__ counts, int n)
{
    for (int i = blockIdx.x * 256 + threadIdx.x; i < n; i += gridDim.x * 256)
        atomicAdd(&counts[dst[i]], 1);
}

// ---------------- CSR build: exclusive scan (2 blocks: ct / cb) -------------
__global__ __launch_bounds__(1024) void scan_kernel(
    const int* __restrict__ counts_ct, const int* __restrict__ counts_cb,
    int* __restrict__ rowptr_ct, int* __restrict__ rowptr_cb, int n)
{
    const int* counts = blockIdx.x ? counts_cb : counts_ct;
    int* rowptr       = blockIdx.x ? rowptr_cb : rowptr_ct;
    __shared__ int sums[1024];
    const int t = threadIdx.x;
    const int chunk = (n + 1023) / 1024;
    const int beg = t * chunk;
    const int end = min(n, beg + chunk);
    int s = 0;
    for (int i = beg; i < end; ++i) s += counts[i];
    sums[t] = s;
    __syncthreads();
    for (int off = 1; off < 1024; off <<= 1) {
        int v = (t >= off) ? sums[t - off] : 0;
        __syncthreads();
        sums[t] += v;
        __syncthreads();
    }
    int run = (t == 0) ? 0 : sums[t - 1];
    for (int i = beg; i < end; ++i) { rowptr[i] = run; run += counts[i]; }
    if (t == 1023) rowptr[n] = sums[1023];
}

// ---------------- CSR build: fill edge ids sorted by dst --------------------
__global__ __launch_bounds__(256) void fill_kernel(
    const int* __restrict__ dst, const int* __restrict__ rowptr,
    int* __restrict__ pos, int* __restrict__ eidx, int n)
{
    for (int i = blockIdx.x * 256 + threadIdx.x; i < n; i += gridDim.x * 256) {
        int d = dst[i];
        int p = rowptr[d] + atomicAdd(&pos[d], 1);
        eidx[p] = i;
    }
}

// ---------------- Gather-side aggregation: one wave per dst node ------------
// lane l owns float2 at offset 2l of the 128-dim accumulator.
__global__ __launch_bounds__(256) void csr_gather_kernel(
    const float* __restrict__ h, const float* __restrict__ feat,
    const int* __restrict__ src, const int* __restrict__ rowptr,
    const int* __restrict__ eidx, float* __restrict__ m, int n_nodes)
{
    const int lane = threadIdx.x & 63;
    const int wave = (blockIdx.x * 256 + threadIdx.x) >> 6;
    const int nwaves = (gridDim.x * 256) >> 6;
    for (int n = wave; n < n_nodes; n += nwaves) {
        const int beg = rowptr[n], end = rowptr[n + 1];
        float2 acc = make_float2(0.0f, 0.0f);
        for (int i0 = beg; i0 < end; i0 += 64) {
            const int cnt = min(64, end - i0);
            int s = 0; float f = 0.0f;
            if (lane < cnt) {
                int id = eidx[i0 + lane];
                s = src[id];
                f = feat[id];
            }
            for (int j = 0; j < cnt; ++j) {
                int   sj = __shfl(s, j);
                float fj = __shfl(f, j);
                float2 v = reinterpret_cast<const float2*>(h + (size_t)sj * HDIM)[lane];
                acc.x = fmaf(fj, v.x, acc.x);
                acc.y = fmaf(fj, v.y, acc.y);
            }
        }
        reinterpret_cast<float2*>(m + (size_t)n * HDIM)[lane] = acc;
    }
}

// ---------------- Fallback: atomic scatter aggregation ----------------------
__global__ __launch_bounds__(256) void edge_agg_kernel(
    const float* __restrict__ h, const float* __restrict__ feat,
    const int* __restrict__ src, const int* __restrict__ dst,
    float* __restrict__ m, int n_edges)
{
    long long tid = (long long)blockIdx.x * 256 + threadIdx.x;
    int e = (int)(tid >> 5);
    if (e >= n_edges) return;
    int q = (int)(tid & 31);
    float f = feat[e];
    size_t s = (size_t)src[e] * HDIM;
    size_t d = (size_t)dst[e] * HDIM;
    float4 v = reinterpret_cast<const float4*>(h + s)[q];
    float* mp = m + d + (size_t)q * 4;
    unsafeAtomicAdd(mp + 0, f * v.x);
    unsafeAtomicAdd(mp + 1, f * v.y);
    unsafeAtomicAdd(mp + 2, f * v.z);
    unsafeAtomicAdd(mp + 3, f * v.w);
}

// -------- Fused GEMM [N,256]x[256,128] + bias + exact GELU + residual -------
// W staged in LDS (128 KB). 8 nodes per iteration; each thread computes the
// same output column for 4 nodes, so each LDS W read is reused 4x.
__global__ __launch_bounds__(256) void gemm_gelu_res_kernel(
    const float* __restrict__ mct, const float* __restrict__ mcb,
    const float* __restrict__ W, const float* __restrict__ bias,
    const float* __restrict__ h_in, float* __restrict__ h_out, int n_nodes)
{
    __shared__ float Wl[256 * HDIM];   // 128 KB
    __shared__ float trow[8][2 * HDIM]; // 8 KB
    for (int i = threadIdx.x; i < 256 * HDIM; i += 256)
        Wl[i] = W[i];
    const int c = threadIdx.x & 127;
    const int g = threadIdx.x >> 7;      // node-group half: 0 -> nodes 0..3, 1 -> 4..7
    const float bc = bias[c];
    __syncthreads();

    const int niter = (n_nodes + 7) >> 3;
    for (int it = blockIdx.x; it < niter; it += gridDim.x) {
        __syncthreads();
        for (int j = threadIdx.x; j < 8 * 256; j += 256) {
            int nn = j >> 8;
            int k  = j & 255;
            long long node = (long long)it * 8 + nn;
            float val = 0.0f;
            if (node < n_nodes)
                val = (k < HDIM) ? mct[node * HDIM + k]
                                 : mcb[node * HDIM + (k - HDIM)];
            trow[nn][k] = val;
        }
        __syncthreads();
        const float* t0 = trow[g * 4 + 0];
        const float* t1 = trow[g * 4 + 1];
        const float* t2 = trow[g * 4 + 2];
        const float* t3 = trow[g * 4 + 3];
        float a0 = bc, a1 = bc, a2 = bc, a3 = bc;
        #pragma unroll 8
        for (int k = 0; k < 256; ++k) {
            float w = Wl[k * HDIM + c];
            a0 = fmaf(t0[k], w, a0);
            a1 = fmaf(t1[k], w, a1);
            a2 = fmaf(t2[k], w, a2);
            a3 = fmaf(t3[k], w, a3);
        }
        float accs[4] = {a0, a1, a2, a3};
        #pragma unroll
        for (int j = 0; j < 4; ++j) {
            long long node = (long long)it * 8 + g * 4 + j;
            if (node < n_nodes) {
                float x = accs[j];
                float gl = 0.5f * x * (1.0f + erff(x * 0.70710678118654752f));
                h_out[node * HDIM + c] = h_in[node * HDIM + c] + gl;
            }
        }
    }
}

extern "C" void kernel_launch(void* const* d_in, const int* in_sizes, int n_in,
                              void* d_out, int out_size, void* d_ws, size_t ws_size,
                              hipStream_t stream)
{
    const float* h0      = (const float*)d_in[0];
    const float* feat_ct = (const float*)d_in[1];
    const float* feat_cb = (const float*)d_in[2];
    const int*   src_ct  = (const int*)d_in[3];
    const int*   dst_ct  = (const int*)d_in[4];
    const int*   src_cb  = (const int*)d_in[5];
    const int*   dst_cb  = (const int*)d_in[6];
    const float* W0      = (const float*)d_in[7];
    const float* b0      = (const float*)d_in[8];
    const float* W1      = (const float*)d_in[9];
    const float* b1      = (const float*)d_in[10];

    const int n_nodes    = in_sizes[0] / HDIM;
    const int n_edges_ct = in_sizes[3];
    const int n_edges_cb = in_sizes[5];
    float* out = (float*)d_out;

    // ---- workspace layout ----
    float* mct = (float*)d_ws;
    float* mcb = mct + (size_t)n_nodes * HDIM;
    int* counts_ct = (int*)(mcb + (size_t)n_nodes * HDIM);
    int* counts_cb = counts_ct + n_nodes;
    int* pos_ct    = counts_cb + n_nodes;
    int* pos_cb    = pos_ct + n_nodes;
    int* rowptr_ct = pos_cb + n_nodes;
    int* rowptr_cb = rowptr_ct + n_nodes + 1;
    int* eidx_ct   = rowptr_cb + n_nodes + 1;
    int* eidx_cb   = eidx_ct + n_edges_ct;
    const size_t need_bytes =
        (size_t)((char*)(eidx_cb + n_edges_cb) - (char*)d_ws);

    const int gemm_blocks = 256;
    const bool use_csr = (ws_size >= need_bytes);

    if (use_csr) {
        // zero counts + pos (contiguous 4*n_nodes ints)
        hipMemsetAsync(counts_ct, 0, (size_t)4 * n_nodes * sizeof(int), stream);
        hist_kernel<<<1024, 256, 0, stream>>>(dst_ct, counts_ct, n_edges_ct);
        hist_kernel<<<1024, 256, 0, stream>>>(dst_cb, counts_cb, n_edges_cb);
        scan_kernel<<<2, 1024, 0, stream>>>(counts_ct, counts_cb,
                                            rowptr_ct, rowptr_cb, n_nodes);
        fill_kernel<<<1024, 256, 0, stream>>>(dst_ct, rowptr_ct, pos_ct,
                                              eidx_ct, n_edges_ct);
        fill_kernel<<<1024, 256, 0, stream>>>(dst_cb, rowptr_cb, pos_cb,
                                              eidx_cb, n_edges_cb);
        const float* hcur = h0;
        for (int layer = 0; layer < 2; ++layer) {
            csr_gather_kernel<<<2048, 256, 0, stream>>>(
                hcur, feat_ct, src_ct, rowptr_ct, eidx_ct, mct, n_nodes);
            csr_gather_kernel<<<2048, 256, 0, stream>>>(
                hcur, feat_cb, src_cb, rowptr_cb, eidx_cb, mcb, n_nodes);
            const float* W = layer ? W1 : W0;
            const float* b = layer ? b1 : b0;
            gemm_gelu_res_kernel<<<gemm_blocks, 256, 0, stream>>>(
                mct, mcb, W, b, hcur, out, n_nodes);
            hcur = out;
        }
    } else {
        // fallback: proven atomic path (needs only mct/mcb)
        const size_t mbytes = (size_t)n_nodes * HDIM * sizeof(float) * 2;
        const int agg_blocks_ct = (int)(((long long)n_edges_ct * 32 + 255) / 256);
        const int agg_blocks_cb = (int)(((long long)n_edges_cb * 32 + 255) / 256);
        const float* hcur = h0;
        for (int layer = 0; layer < 2; ++layer) {
            hipMemsetAsync(d_ws, 0, mbytes, stream);
            edge_agg_kernel<<<agg_blocks_ct, 256, 0, stream>>>(
                hcur, feat_ct, src_ct, dst_ct, mct, n_edges_ct);
            edge_agg_kernel<<<agg_blocks_cb, 256, 0, stream>>>(
                hcur, feat_cb, src_cb, dst_cb, mcb, n_edges_cb);
            const float* W = layer ? W1 : W0;
            const float* b = layer ? b1 : b0;
            gemm_gelu_res_kernel<<<gemm_blocks, 256, 0, stream>>>(
                mct, mcb, W, b, hcur, out, n_nodes);
            hcur = out;
        }
    }
}

// Round 4
// 602.880 us; speedup vs baseline: 10.0750x; 1.7458x over previous
//
#include <hip/hip_runtime.h>
#include <math.h>

#define HDIM 128
typedef unsigned int uint;
using short8 = __attribute__((ext_vector_type(8))) short;
using f32x4  = __attribute__((ext_vector_type(4))) float;

__device__ __forceinline__ uint pack_bf16x2(float a, float b) {
    uint ua = __float_as_uint(a), ub = __float_as_uint(b);
    ua = (ua + 0x7fffu + ((ua >> 16) & 1u)) >> 16;
    ub = (ub + 0x7fffu + ((ub >> 16) & 1u)) & 0xffff0000u;
    return ua | ub;
}
__device__ __forceinline__ unsigned short pack_bf16(float a) {
    uint ua = __float_as_uint(a);
    return (unsigned short)((ua + 0x7fffu + ((ua >> 16) & 1u)) >> 16);
}

// ---------------- fp32 h -> bf16 (packed pairs) ----------------
__global__ __launch_bounds__(256) void conv_h_kernel(
    const float* __restrict__ h, uint* __restrict__ hb, int n_pairs)
{
    for (int i = blockIdx.x * 256 + threadIdx.x; i < n_pairs; i += gridDim.x * 256) {
        float2 v = reinterpret_cast<const float2*>(h)[i];
        hb[i] = pack_bf16x2(v.x, v.y);
    }
}

// ------------- W [256][128] fp32 -> Wt [128][256] bf16 (both layers) --------
__global__ __launch_bounds__(256) void conv_w_kernel(
    const float* __restrict__ W0, const float* __restrict__ W1,
    unsigned short* __restrict__ Wt0, unsigned short* __restrict__ Wt1)
{
    for (int i = blockIdx.x * 256 + threadIdx.x; i < 2 * 32768; i += gridDim.x * 256) {
        const float* W = (i < 32768) ? W0 : W1;
        unsigned short* Wt = (i < 32768) ? Wt0 : Wt1;
        int j = i & 32767;
        int c = j >> 8, k = j & 255;
        Wt[j] = pack_bf16(W[k * HDIM + c]);
    }
}

// ---------------- CSR build ----------------
__global__ __launch_bounds__(256) void hist_kernel(
    const int* __restrict__ dst, int* __restrict__ counts, int n)
{
    for (int i = blockIdx.x * 256 + threadIdx.x; i < n; i += gridDim.x * 256)
        atomicAdd(&counts[dst[i]], 1);
}

__global__ __launch_bounds__(1024) void scan_kernel(
    const int* __restrict__ counts_ct, const int* __restrict__ counts_cb,
    int* __restrict__ rowptr_ct, int* __restrict__ rowptr_cb, int n)
{
    const int* counts = blockIdx.x ? counts_cb : counts_ct;
    int* rowptr       = blockIdx.x ? rowptr_cb : rowptr_ct;
    __shared__ int sums[1024];
    const int t = threadIdx.x;
    const int chunk = (n + 1023) / 1024;
    const int beg = t * chunk;
    const int end = min(n, beg + chunk);
    int s = 0;
    for (int i = beg; i < end; ++i) s += counts[i];
    sums[t] = s;
    __syncthreads();
    for (int off = 1; off < 1024; off <<= 1) {
        int v = (t >= off) ? sums[t - off] : 0;
        __syncthreads();
        sums[t] += v;
        __syncthreads();
    }
    int run = (t == 0) ? 0 : sums[t - 1];
    for (int i = beg; i < end; ++i) { rowptr[i] = run; run += counts[i]; }
    if (t == 1023) rowptr[n] = sums[1023];
}

// fill: materialize dst-sorted (src, feat) arrays — no indirection at gather
__global__ __launch_bounds__(256) void fill_kernel(
    const int* __restrict__ dst, const int* __restrict__ src,
    const float* __restrict__ feat, const int* __restrict__ rowptr,
    int* __restrict__ pos, int* __restrict__ csr_src,
    float* __restrict__ csr_feat, int n)
{
    for (int i = blockIdx.x * 256 + threadIdx.x; i < n; i += gridDim.x * 256) {
        int d = dst[i];
        int p = rowptr[d] + atomicAdd(&pos[d], 1);
        csr_src[p]  = src[i];
        csr_feat[p] = feat[i];
    }
}

// ------ Gather aggregation, both edge types, bf16 h in / bf16 m out ---------
// one wave per (type, dst node); lane owns a packed bf16 pair of the 128-dim row
__global__ __launch_bounds__(256) void csr_gather_bf16_kernel(
    const uint* __restrict__ hb,
    const int* __restrict__ rp_ct, const int* __restrict__ es_ct, const float* __restrict__ ef_ct,
    const int* __restrict__ rp_cb, const int* __restrict__ es_cb, const float* __restrict__ ef_cb,
    uint* __restrict__ mct, uint* __restrict__ mcb, int n_nodes)
{
    const int lane = threadIdx.x & 63;
    const int wave = (blockIdx.x * 256 + threadIdx.x) >> 6;
    const int nwaves = (gridDim.x * 256) >> 6;
    const int total = 2 * n_nodes;
    for (int v = wave; v < total; v += nwaves) {
        const bool cb = (v >= n_nodes);
        const int n = cb ? (v - n_nodes) : v;
        const int* rp  = cb ? rp_cb : rp_ct;
        const int* es  = cb ? es_cb : es_ct;
        const float* ef = cb ? ef_cb : ef_ct;
        uint* m = cb ? mcb : mct;
        const int beg = rp[n], end = rp[n + 1];
        float accx = 0.0f, accy = 0.0f;
        for (int i0 = beg; i0 < end; i0 += 64) {
            const int cnt = min(64, end - i0);
            int s = 0; float f = 0.0f;
            if (lane < cnt) { s = es[i0 + lane]; f = ef[i0 + lane]; }
            #pragma unroll 4
            for (int j = 0; j < cnt; ++j) {
                int   sj = __shfl(s, j);
                float fj = __shfl(f, j);
                uint hv = hb[(size_t)sj * 64 + lane];
                float lo = __uint_as_float(hv << 16);
                float hi = __uint_as_float(hv & 0xffff0000u);
                accx = fmaf(fj, lo, accx);
                accy = fmaf(fj, hi, accy);
            }
        }
        m[(size_t)n * 64 + lane] = pack_bf16x2(accx, accy);
    }
}

// -------- MFMA GEMM: t=[mct|mcb] (bf16) @ W (bf16) + bias, GELU, residual ---
// block: 128 nodes x 128 cols, 4 waves in 2x2, K=256. fp32 accumulate.
#define APITCH 264   // bf16 units; 528B row stride -> 2-way max bank alias
__global__ __launch_bounds__(256) void gemm_mfma_kernel(
    const unsigned short* __restrict__ mct, const unsigned short* __restrict__ mcb,
    const unsigned short* __restrict__ Wt, const float* __restrict__ bias,
    const float* __restrict__ h_in, float* __restrict__ h_out,
    unsigned short* __restrict__ hb_out, int n_nodes)
{
    __shared__ unsigned short At[128 * APITCH];
    __shared__ unsigned short Bt[128 * APITCH];

    const int base = blockIdx.x * 128;
    // stage A: 128 rows x 256 bf16 (k<128 from mct, k>=128 from mcb)
    for (int j = threadIdx.x; j < 128 * 32; j += 256) {
        int r = j >> 5, ch = j & 31;
        int node = base + r;
        uint4 v = make_uint4(0, 0, 0, 0);
        if (node < n_nodes) {
            v = (ch < 16)
                ? reinterpret_cast<const uint4*>(mct + (size_t)node * HDIM)[ch]
                : reinterpret_cast<const uint4*>(mcb + (size_t)node * HDIM)[ch - 16];
        }
        *reinterpret_cast<uint4*>(&At[r * APITCH + ch * 8]) = v;
    }
    // stage B: Wt[c][k] 128 x 256 bf16
    for (int j = threadIdx.x; j < 128 * 32; j += 256) {
        int c = j >> 5, ch = j & 31;
        uint4 v = reinterpret_cast<const uint4*>(Wt + (size_t)c * 256)[ch];
        *reinterpret_cast<uint4*>(&Bt[c * APITCH + ch * 8]) = v;
    }
    __syncthreads();

    const int lane = threadIdx.x & 63;
    const int wid  = threadIdx.x >> 6;
    const int wm = wid >> 1, wn = wid & 1;
    const int lr = lane & 15, lg = lane >> 4;

    f32x4 acc[4][4];
    #pragma unroll
    for (int mi = 0; mi < 4; ++mi)
        #pragma unroll
        for (int ni = 0; ni < 4; ++ni)
            acc[mi][ni] = (f32x4){0.f, 0.f, 0.f, 0.f};

    #pragma unroll
    for (int ks = 0; ks < 8; ++ks) {
        const int k0 = ks * 32;
        short8 a[4], b[4];
        #pragma unroll
        for (int mi = 0; mi < 4; ++mi)
            a[mi] = *reinterpret_cast<const short8*>(
                &At[(wm * 64 + mi * 16 + lr) * APITCH + k0 + lg * 8]);
        #pragma unroll
        for (int ni = 0; ni < 4; ++ni)
            b[ni] = *reinterpret_cast<const short8*>(
                &Bt[(wn * 64 + ni * 16 + lr) * APITCH + k0 + lg * 8]);
        #pragma unroll
        for (int mi = 0; mi < 4; ++mi)
            #pragma unroll
            for (int ni = 0; ni < 4; ++ni)
                acc[mi][ni] = __builtin_amdgcn_mfma_f32_16x16x32_bf16(
                    a[mi], b[ni], acc[mi][ni], 0, 0, 0);
    }

    // epilogue: C[row=(lane>>4)*4+reg][col=lane&15] per fragment
    #pragma unroll
    for (int mi = 0; mi < 4; ++mi) {
        #pragma unroll
        for (int ni = 0; ni < 4; ++ni) {
            const int col = wn * 64 + ni * 16 + lr;
            const float bc = bias[col];
            #pragma unroll
            for (int j = 0; j < 4; ++j) {
                int node = base + wm * 64 + mi * 16 + lg * 4 + j;
                if (node < n_nodes) {
                    float x = acc[mi][ni][j] + bc;
                    float g = 0.5f * x * (1.0f + erff(x * 0.70710678118654752f));
                    float o = h_in[(size_t)node * HDIM + col] + g;
                    h_out[(size_t)node * HDIM + col] = o;
                    hb_out[(size_t)node * HDIM + col] = pack_bf16(o);
                }
            }
        }
    }
}

// ---------------- Fallback path kernels (ws too small) ----------------------
__global__ __launch_bounds__(256) void edge_agg_kernel(
    const float* __restrict__ h, const float* __restrict__ feat,
    const int* __restrict__ src, const int* __restrict__ dst,
    float* __restrict__ m, int n_edges)
{
    long long tid = (long long)blockIdx.x * 256 + threadIdx.x;
    int e = (int)(tid >> 5);
    if (e >= n_edges) return;
    int q = (int)(tid & 31);
    float f = feat[e];
    size_t s = (size_t)src[e] * HDIM;
    size_t d = (size_t)dst[e] * HDIM;
    float4 v = reinterpret_cast<const float4*>(h + s)[q];
    float* mp = m + d + (size_t)q * 4;
    unsafeAtomicAdd(mp + 0, f * v.x);
    unsafeAtomicAdd(mp + 1, f * v.y);
    unsafeAtomicAdd(mp + 2, f * v.z);
    unsafeAtomicAdd(mp + 3, f * v.w);
}

__global__ __launch_bounds__(256) void gemm_gelu_res_kernel(
    const float* __restrict__ mct, const float* __restrict__ mcb,
    const float* __restrict__ W, const float* __restrict__ bias,
    const float* __restrict__ h_in, float* __restrict__ h_out, int n_nodes)
{
    __shared__ float Wl[256 * HDIM];
    __shared__ float trow[8][2 * HDIM];
    for (int i = threadIdx.x; i < 256 * HDIM; i += 256)
        Wl[i] = W[i];
    const int c = threadIdx.x & 127;
    const int g = threadIdx.x >> 7;
    const float bc = bias[c];
    __syncthreads();
    const int niter = (n_nodes + 7) >> 3;
    for (int it = blockIdx.x; it < niter; it += gridDim.x) {
        __syncthreads();
        for (int j = threadIdx.x; j < 8 * 256; j += 256) {
            int nn = j >> 8;
            int k  = j & 255;
            long long node = (long long)it * 8 + nn;
            float val = 0.0f;
            if (node < n_nodes)
                val = (k < HDIM) ? mct[node * HDIM + k]
                                 : mcb[node * HDIM + (k - HDIM)];
            trow[nn][k] = val;
        }
        __syncthreads();
        const float* t0 = trow[g * 4 + 0];
        const float* t1 = trow[g * 4 + 1];
        const float* t2 = trow[g * 4 + 2];
        const float* t3 = trow[g * 4 + 3];
        float a0 = bc, a1 = bc, a2 = bc, a3 = bc;
        #pragma unroll 8
        for (int k = 0; k < 256; ++k) {
            float w = Wl[k * HDIM + c];
            a0 = fmaf(t0[k], w, a0);
            a1 = fmaf(t1[k], w, a1);
            a2 = fmaf(t2[k], w, a2);
            a3 = fmaf(t3[k], w, a3);
        }
        float accs[4] = {a0, a1, a2, a3};
        #pragma unroll
        for (int j = 0; j < 4; ++j) {
            long long node = (long long)it * 8 + g * 4 + j;
            if (node < n_nodes) {
                float x = accs[j];
                float gl = 0.5f * x * (1.0f + erff(x * 0.70710678118654752f));
                h_out[node * HDIM + c] = h_in[node * HDIM + c] + gl;
            }
        }
    }
}

extern "C" void kernel_launch(void* const* d_in, const int* in_sizes, int n_in,
                              void* d_out, int out_size, void* d_ws, size_t ws_size,
                              hipStream_t stream)
{
    const float* h0      = (const float*)d_in[0];
    const float* feat_ct = (const float*)d_in[1];
    const float* feat_cb = (const float*)d_in[2];
    const int*   src_ct  = (const int*)d_in[3];
    const int*   dst_ct  = (const int*)d_in[4];
    const int*   src_cb  = (const int*)d_in[5];
    const int*   dst_cb  = (const int*)d_in[6];
    const float* W0      = (const float*)d_in[7];
    const float* b0      = (const float*)d_in[8];
    const float* W1      = (const float*)d_in[9];
    const float* b1      = (const float*)d_in[10];

    const int n_nodes    = in_sizes[0] / HDIM;
    const int n_edges_ct = in_sizes[3];
    const int n_edges_cb = in_sizes[5];
    float* out = (float*)d_out;

    // ---- workspace layout (256B-aligned chunks) ----
    char* p = (char*)d_ws;
    auto take = [&](size_t bytes) -> char* {
        char* r = p;
        p += (bytes + 255) & ~(size_t)255;
        return r;
    };
    unsigned short* hb   = (unsigned short*)take((size_t)n_nodes * HDIM * 2);
    unsigned short* mctb = (unsigned short*)take((size_t)n_nodes * HDIM * 2);
    unsigned short* mcbb = (unsigned short*)take((size_t)n_nodes * HDIM * 2);
    unsigned short* Wt0  = (unsigned short*)take(32768 * 2);
    unsigned short* Wt1  = (unsigned short*)take(32768 * 2);
    int* counts_ct = (int*)take((size_t)n_nodes * 4);
    int* counts_cb = (int*)take((size_t)n_nodes * 4);
    int* pos_ct    = (int*)take((size_t)n_nodes * 4);
    int* pos_cb    = (int*)take((size_t)n_nodes * 4);
    int* rowptr_ct = (int*)take(((size_t)n_nodes + 1) * 4);
    int* rowptr_cb = (int*)take(((size_t)n_nodes + 1) * 4);
    int*   es_ct = (int*)take((size_t)n_edges_ct * 4);
    float* ef_ct = (float*)take((size_t)n_edges_ct * 4);
    int*   es_cb = (int*)take((size_t)n_edges_cb * 4);
    float* ef_cb = (float*)take((size_t)n_edges_cb * 4);
    const size_t need_bytes = (size_t)(p - (char*)d_ws);

    if (ws_size >= need_bytes) {
        conv_h_kernel<<<2048, 256, 0, stream>>>((const float*)h0, (uint*)hb,
                                                n_nodes * (HDIM / 2));
        conv_w_kernel<<<64, 256, 0, stream>>>(W0, W1, Wt0, Wt1);
        // zero counts_ct..pos_cb INCLUDING the 256B alignment padding between
        // them (R3 bug: memset of 4*n_nodes ints left pos_cb's tail poisoned)
        const size_t zero_span = (size_t)((char*)(pos_cb + n_nodes) - (char*)counts_ct);
        hipMemsetAsync(counts_ct, 0, zero_span, stream);
        hist_kernel<<<1024, 256, 0, stream>>>(dst_ct, counts_ct, n_edges_ct);
        hist_kernel<<<1024, 256, 0, stream>>>(dst_cb, counts_cb, n_edges_cb);
        scan_kernel<<<2, 1024, 0, stream>>>(counts_ct, counts_cb,
                                            rowptr_ct, rowptr_cb, n_nodes);
        fill_kernel<<<1024, 256, 0, stream>>>(dst_ct, src_ct, feat_ct, rowptr_ct,
                                              pos_ct, es_ct, ef_ct, n_edges_ct);
        fill_kernel<<<1024, 256, 0, stream>>>(dst_cb, src_cb, feat_cb, rowptr_cb,
                                              pos_cb, es_cb, ef_cb, n_edges_cb);
        const int gemm_blocks = (n_nodes + 127) / 128;
        const float* hin = h0;
        for (int layer = 0; layer < 2; ++layer) {
            csr_gather_bf16_kernel<<<2048, 256, 0, stream>>>(
                (const uint*)hb, rowptr_ct, es_ct, ef_ct,
                rowptr_cb, es_cb, ef_cb, (uint*)mctb, (uint*)mcbb, n_nodes);
            gemm_mfma_kernel<<<gemm_blocks, 256, 0, stream>>>(
                mctb, mcbb, layer ? Wt1 : Wt0, layer ? b1 : b0,
                hin, out, hb, n_nodes);
            hin = out;
        }
    } else {
        // fallback: proven atomic + fp32 path
        float* mct = (float*)d_ws;
        float* mcb = mct + (size_t)n_nodes * HDIM;
        const size_t mbytes = (size_t)n_nodes * HDIM * sizeof(float) * 2;
        const int agg_blocks_ct = (int)(((long long)n_edges_ct * 32 + 255) / 256);
        const int agg_blocks_cb = (int)(((long long)n_edges_cb * 32 + 255) / 256);
        const float* hcur = h0;
        for (int layer = 0; layer < 2; ++layer) {
            hipMemsetAsync(d_ws, 0, mbytes, stream);
            edge_agg_kernel<<<agg_blocks_ct, 256, 0, stream>>>(
                hcur, feat_ct, src_ct, dst_ct, mct, n_edges_ct);
            edge_agg_kernel<<<agg_blocks_cb, 256, 0, stream>>>(
                hcur, feat_cb, src_cb, dst_cb, mcb, n_edges_cb);
            gemm_gelu_res_kernel<<<256, 256, 0, stream>>>(
                mct, mcb, layer ? W1 : W0, layer ? b1 : b0, hcur, out, n_nodes);
            hcur = out;
        }
    }
}

// Round 5
// 519.713 us; speedup vs baseline: 11.6873x; 1.1600x over previous
//
#include <hip/hip_runtime.h>
#include <math.h>

#define HDIM 128
typedef unsigned int uint;
using short8 = __attribute__((ext_vector_type(8))) short;
using f32x4  = __attribute__((ext_vector_type(4))) float;

__device__ __forceinline__ uint pack_bf16x2(float a, float b) {
    uint ua = __float_as_uint(a), ub = __float_as_uint(b);
    ua = (ua + 0x7fffu + ((ua >> 16) & 1u)) >> 16;
    ub = (ub + 0x7fffu + ((ub >> 16) & 1u)) & 0xffff0000u;
    return ua | ub;
}
__device__ __forceinline__ unsigned short pack_bf16(float a) {
    uint ua = __float_as_uint(a);
    return (unsigned short)((ua + 0x7fffu + ((ua >> 16) & 1u)) >> 16);
}

// ---- fp32 h -> bf16 pairs, and W [256][128] fp32 -> Wt [128][256] bf16 -----
__global__ __launch_bounds__(256) void conv_all_kernel(
    const float* __restrict__ h, uint* __restrict__ hb, int n_pairs,
    const float* __restrict__ W0, const float* __restrict__ W1,
    unsigned short* __restrict__ Wt0, unsigned short* __restrict__ Wt1)
{
    const int total = n_pairs + 2 * 32768;
    for (int i = blockIdx.x * 256 + threadIdx.x; i < total; i += gridDim.x * 256) {
        if (i < n_pairs) {
            float2 v = reinterpret_cast<const float2*>(h)[i];
            hb[i] = pack_bf16x2(v.x, v.y);
        } else {
            int t = i - n_pairs;
            const float* W = (t < 32768) ? W0 : W1;
            unsigned short* Wt = (t < 32768) ? Wt0 : Wt1;
            int j = t & 32767;
            int c = j >> 8, k = j & 255;
            Wt[j] = pack_bf16(W[k * HDIM + c]);
        }
    }
}

// ---------------- CSR build: fused histogram (both edge types) --------------
__global__ __launch_bounds__(256) void hist_kernel(
    const int* __restrict__ dst_ct, int* __restrict__ counts_ct, int n_ct,
    const int* __restrict__ dst_cb, int* __restrict__ counts_cb, int n_cb)
{
    const int total = n_ct + n_cb;
    for (int i = blockIdx.x * 256 + threadIdx.x; i < total; i += gridDim.x * 256) {
        if (i < n_ct) atomicAdd(&counts_ct[dst_ct[i]], 1);
        else          atomicAdd(&counts_cb[dst_cb[i - n_ct]], 1);
    }
}

__global__ __launch_bounds__(1024) void scan_kernel(
    const int* __restrict__ counts_ct, const int* __restrict__ counts_cb,
    int* __restrict__ rowptr_ct, int* __restrict__ rowptr_cb, int n)
{
    const int* counts = blockIdx.x ? counts_cb : counts_ct;
    int* rowptr       = blockIdx.x ? rowptr_cb : rowptr_ct;
    __shared__ int sums[1024];
    const int t = threadIdx.x;
    const int chunk = (n + 1023) / 1024;
    const int beg = t * chunk;
    const int end = min(n, beg + chunk);
    int s = 0;
    for (int i = beg; i < end; ++i) s += counts[i];
    sums[t] = s;
    __syncthreads();
    for (int off = 1; off < 1024; off <<= 1) {
        int v = (t >= off) ? sums[t - off] : 0;
        __syncthreads();
        sums[t] += v;
        __syncthreads();
    }
    int run = (t == 0) ? 0 : sums[t - 1];
    for (int i = beg; i < end; ++i) { rowptr[i] = run; run += counts[i]; }
    if (t == 1023) rowptr[n] = sums[1023];
}

// fill: materialize dst-sorted packed (src, feat) int2 records, both types
__global__ __launch_bounds__(256) void fill_kernel(
    const int* __restrict__ dst_ct, const int* __restrict__ src_ct,
    const float* __restrict__ feat_ct, const int* __restrict__ rowptr_ct,
    int* __restrict__ pos_ct, int2* __restrict__ ecsr_ct, int n_ct,
    const int* __restrict__ dst_cb, const int* __restrict__ src_cb,
    const float* __restrict__ feat_cb, const int* __restrict__ rowptr_cb,
    int* __restrict__ pos_cb, int2* __restrict__ ecsr_cb, int n_cb)
{
    const int total = n_ct + n_cb;
    for (int i = blockIdx.x * 256 + threadIdx.x; i < total; i += gridDim.x * 256) {
        if (i < n_ct) {
            int d = dst_ct[i];
            int p = rowptr_ct[d] + atomicAdd(&pos_ct[d], 1);
            ecsr_ct[p] = make_int2(src_ct[i], __float_as_int(feat_ct[i]));
        } else {
            int k = i - n_ct;
            int d = dst_cb[k];
            int p = rowptr_cb[d] + atomicAdd(&pos_cb[d], 1);
            ecsr_cb[p] = make_int2(src_cb[k], __float_as_int(feat_cb[k]));
        }
    }
}

// ------ Gather aggregation, both edge types, bf16 h in / bf16 m out ---------
__global__ __launch_bounds__(256) void csr_gather_bf16_kernel(
    const uint* __restrict__ hb,
    const int* __restrict__ rp_ct, const int2* __restrict__ e_ct,
    const int* __restrict__ rp_cb, const int2* __restrict__ e_cb,
    uint* __restrict__ mct, uint* __restrict__ mcb, int n_nodes)
{
    const int lane = threadIdx.x & 63;
    const int wave = (blockIdx.x * 256 + threadIdx.x) >> 6;
    const int nwaves = (gridDim.x * 256) >> 6;
    const int total = 2 * n_nodes;
    for (int v = wave; v < total; v += nwaves) {
        const bool cb = (v >= n_nodes);
        const int n = cb ? (v - n_nodes) : v;
        const int* rp    = cb ? rp_cb : rp_ct;
        const int2* ecsr = cb ? e_cb : e_ct;
        uint* m = cb ? mcb : mct;
        const int beg = rp[n], end = rp[n + 1];
        float accx = 0.0f, accy = 0.0f;
        for (int i0 = beg; i0 < end; i0 += 64) {
            const int cnt = min(64, end - i0);
            int s = 0; float f = 0.0f;
            if (lane < cnt) {
                int2 e = ecsr[i0 + lane];
                s = e.x;
                f = __int_as_float(e.y);
            }
            #pragma unroll 4
            for (int j = 0; j < cnt; ++j) {
                int   sj = __shfl(s, j);
                float fj = __shfl(f, j);
                uint hv = hb[(size_t)sj * 64 + lane];
                float lo = __uint_as_float(hv << 16);
                float hi = __uint_as_float(hv & 0xffff0000u);
                accx = fmaf(fj, lo, accx);
                accy = fmaf(fj, hi, accy);
            }
        }
        m[(size_t)n * 64 + lane] = pack_bf16x2(accx, accy);
    }
}

// -------- Zero-LDS MFMA GEMM: t=[mct|mcb] bf16 @ Wt bf16 + bias/GELU/res ----
// 391 blocks x 128 nodes; 4 waves 2x2; fragments loaded straight from global
// (A has no K-reuse; Wt is 64KB and L2-hot). No __shared__, no barriers.
__global__ __launch_bounds__(256) void gemm_mfma_kernel(
    const unsigned short* __restrict__ mct, const unsigned short* __restrict__ mcb,
    const unsigned short* __restrict__ Wt, const float* __restrict__ bias,
    const float* __restrict__ h_in, float* __restrict__ h_out,
    unsigned short* __restrict__ hb_out, int n_nodes, int write_hb)
{
    const int base = blockIdx.x * 128;
    const int lane = threadIdx.x & 63;
    const int wid  = threadIdx.x >> 6;
    const int wm = wid >> 1, wn = wid & 1;
    const int lr = lane & 15, lg = lane >> 4;

    f32x4 acc[4][4];
    #pragma unroll
    for (int mi = 0; mi < 4; ++mi)
        #pragma unroll
        for (int ni = 0; ni < 4; ++ni)
            acc[mi][ni] = (f32x4){0.f, 0.f, 0.f, 0.f};

    const int last_block = (base + 128 > n_nodes);

    #pragma unroll
    for (int ks = 0; ks < 8; ++ks) {
        const int k0 = ks * 32;          // k in [0,256)
        const int koff = k0 + lg * 8;    // 16B-aligned, never crosses 128
        short8 a[4], b[4];
        #pragma unroll
        for (int mi = 0; mi < 4; ++mi) {
            int node = base + wm * 64 + mi * 16 + lr;
            if (last_block && node >= n_nodes) node = n_nodes - 1; // clamp: avoid OOB
            const unsigned short* srcp = (koff < 128)
                ? (mct + (size_t)node * HDIM + koff)
                : (mcb + (size_t)node * HDIM + (koff - 128));
            a[mi] = *reinterpret_cast<const short8*>(srcp);
        }
        #pragma unroll
        for (int ni = 0; ni < 4; ++ni) {
            int col = wn * 64 + ni * 16 + lr;
            b[ni] = *reinterpret_cast<const short8*>(Wt + (size_t)col * 256 + koff);
        }
        #pragma unroll
        for (int mi = 0; mi < 4; ++mi)
            #pragma unroll
            for (int ni = 0; ni < 4; ++ni)
                acc[mi][ni] = __builtin_amdgcn_mfma_f32_16x16x32_bf16(
                    a[mi], b[ni], acc[mi][ni], 0, 0, 0);
    }

    // epilogue: C[row=(lane>>4)*4+reg][col=lane&15] per fragment
    #pragma unroll
    for (int mi = 0; mi < 4; ++mi) {
        #pragma unroll
        for (int ni = 0; ni < 4; ++ni) {
            const int col = wn * 64 + ni * 16 + lr;
            const float bc = bias[col];
            #pragma unroll
            for (int j = 0; j < 4; ++j) {
                int node = base + wm * 64 + mi * 16 + lg * 4 + j;
                if (node < n_nodes) {
                    float x = acc[mi][ni][j] + bc;
                    float g = 0.5f * x * (1.0f + erff(x * 0.70710678118654752f));
                    float o = h_in[(size_t)node * HDIM + col] + g;
                    h_out[(size_t)node * HDIM + col] = o;
                    if (write_hb)
                        hb_out[(size_t)node * HDIM + col] = pack_bf16(o);
                }
            }
        }
    }
}

// ---------------- Fallback path kernels (ws too small) ----------------------
__global__ __launch_bounds__(256) void edge_agg_kernel(
    const float* __restrict__ h, const float* __restrict__ feat,
    const int* __restrict__ src, const int* __restrict__ dst,
    float* __restrict__ m, int n_edges)
{
    long long tid = (long long)blockIdx.x * 256 + threadIdx.x;
    int e = (int)(tid >> 5);
    if (e >= n_edges) return;
    int q = (int)(tid & 31);
    float f = feat[e];
    size_t s = (size_t)src[e] * HDIM;
    size_t d = (size_t)dst[e] * HDIM;
    float4 v = reinterpret_cast<const float4*>(h + s)[q];
    float* mp = m + d + (size_t)q * 4;
    unsafeAtomicAdd(mp + 0, f * v.x);
    unsafeAtomicAdd(mp + 1, f * v.y);
    unsafeAtomicAdd(mp + 2, f * v.z);
    unsafeAtomicAdd(mp + 3, f * v.w);
}

__global__ __launch_bounds__(256) void gemm_gelu_res_kernel(
    const float* __restrict__ mct, const float* __restrict__ mcb,
    const float* __restrict__ W, const float* __restrict__ bias,
    const float* __restrict__ h_in, float* __restrict__ h_out, int n_nodes)
{
    __shared__ float Wl[256 * HDIM];
    __shared__ float trow[8][2 * HDIM];
    for (int i = threadIdx.x; i < 256 * HDIM; i += 256)
        Wl[i] = W[i];
    const int c = threadIdx.x & 127;
    const int g = threadIdx.x >> 7;
    const float bc = bias[c];
    __syncthreads();
    const int niter = (n_nodes + 7) >> 3;
    for (int it = blockIdx.x; it < niter; it += gridDim.x) {
        __syncthreads();
        for (int j = threadIdx.x; j < 8 * 256; j += 256) {
            int nn = j >> 8;
            int k  = j & 255;
            long long node = (long long)it * 8 + nn;
            float val = 0.0f;
            if (node < n_nodes)
                val = (k < HDIM) ? mct[node * HDIM + k]
                                 : mcb[node * HDIM + (k - HDIM)];
            trow[nn][k] = val;
        }
        __syncthreads();
        const float* t0 = trow[g * 4 + 0];
        const float* t1 = trow[g * 4 + 1];
        const float* t2 = trow[g * 4 + 2];
        const float* t3 = trow[g * 4 + 3];
        float a0 = bc, a1 = bc, a2 = bc, a3 = bc;
        #pragma unroll 8
        for (int k = 0; k < 256; ++k) {
            float w = Wl[k * HDIM + c];
            a0 = fmaf(t0[k], w, a0);
            a1 = fmaf(t1[k], w, a1);
            a2 = fmaf(t2[k], w, a2);
            a3 = fmaf(t3[k], w, a3);
        }
        float accs[4] = {a0, a1, a2, a3};
        #pragma unroll
        for (int j = 0; j < 4; ++j) {
            long long node = (long long)it * 8 + g * 4 + j;
            if (node < n_nodes) {
                float x = accs[j];
                float gl = 0.5f * x * (1.0f + erff(x * 0.70710678118654752f));
                h_out[node * HDIM + c] = h_in[node * HDIM + c] + gl;
            }
        }
    }
}

extern "C" void kernel_launch(void* const* d_in, const int* in_sizes, int n_in,
                              void* d_out, int out_size, void* d_ws, size_t ws_size,
                              hipStream_t stream)
{
    const float* h0      = (const float*)d_in[0];
    const float* feat_ct = (const float*)d_in[1];
    const float* feat_cb = (const float*)d_in[2];
    const int*   src_ct  = (const int*)d_in[3];
    const int*   dst_ct  = (const int*)d_in[4];
    const int*   src_cb  = (const int*)d_in[5];
    const int*   dst_cb  = (const int*)d_in[6];
    const float* W0      = (const float*)d_in[7];
    const float* b0      = (const float*)d_in[8];
    const float* W1      = (const float*)d_in[9];
    const float* b1      = (const float*)d_in[10];

    const int n_nodes    = in_sizes[0] / HDIM;
    const int n_edges_ct = in_sizes[3];
    const int n_edges_cb = in_sizes[5];
    float* out = (float*)d_out;

    // ---- workspace layout (256B-aligned chunks) ----
    char* p = (char*)d_ws;
    auto take = [&](size_t bytes) -> char* {
        char* r = p;
        p += (bytes + 255) & ~(size_t)255;
        return r;
    };
    unsigned short* hb   = (unsigned short*)take((size_t)n_nodes * HDIM * 2);
    unsigned short* mctb = (unsigned short*)take((size_t)n_nodes * HDIM * 2);
    unsigned short* mcbb = (unsigned short*)take((size_t)n_nodes * HDIM * 2);
    unsigned short* Wt0  = (unsigned short*)take(32768 * 2);
    unsigned short* Wt1  = (unsigned short*)take(32768 * 2);
    int* counts_ct = (int*)take((size_t)n_nodes * 4);
    int* counts_cb = (int*)take((size_t)n_nodes * 4);
    int* pos_ct    = (int*)take((size_t)n_nodes * 4);
    int* pos_cb    = (int*)take((size_t)n_nodes * 4);
    int* rowptr_ct = (int*)take(((size_t)n_nodes + 1) * 4);
    int* rowptr_cb = (int*)take(((size_t)n_nodes + 1) * 4);
    int2* ecsr_ct = (int2*)take((size_t)n_edges_ct * 8);
    int2* ecsr_cb = (int2*)take((size_t)n_edges_cb * 8);
    const size_t need_bytes = (size_t)(p - (char*)d_ws);

    if (ws_size >= need_bytes) {
        conv_all_kernel<<<2048, 256, 0, stream>>>(
            h0, (uint*)hb, n_nodes * (HDIM / 2), W0, W1, Wt0, Wt1);
        // zero counts..pos INCLUDING alignment padding between them
        const size_t zero_span = (size_t)((char*)(pos_cb + n_nodes) - (char*)counts_ct);
        hipMemsetAsync(counts_ct, 0, zero_span, stream);
        hist_kernel<<<1024, 256, 0, stream>>>(dst_ct, counts_ct, n_edges_ct,
                                              dst_cb, counts_cb, n_edges_cb);
        scan_kernel<<<2, 1024, 0, stream>>>(counts_ct, counts_cb,
                                            rowptr_ct, rowptr_cb, n_nodes);
        fill_kernel<<<1024, 256, 0, stream>>>(
            dst_ct, src_ct, feat_ct, rowptr_ct, pos_ct, ecsr_ct, n_edges_ct,
            dst_cb, src_cb, feat_cb, rowptr_cb, pos_cb, ecsr_cb, n_edges_cb);
        const int gemm_blocks = (n_nodes + 127) / 128;
        const float* hin = h0;
        for (int layer = 0; layer < 2; ++layer) {
            csr_gather_bf16_kernel<<<2048, 256, 0, stream>>>(
                (const uint*)hb, rowptr_ct, ecsr_ct, rowptr_cb, ecsr_cb,
                (uint*)mctb, (uint*)mcbb, n_nodes);
            gemm_mfma_kernel<<<gemm_blocks, 256, 0, stream>>>(
                mctb, mcbb, layer ? Wt1 : Wt0, layer ? b1 : b0,
                hin, out, hb, n_nodes, layer == 0 ? 1 : 0);
            hin = out;
        }
    } else {
        // fallback: proven atomic + fp32 path
        float* mct = (float*)d_ws;
        float* mcb = mct + (size_t)n_nodes * HDIM;
        const size_t mbytes = (size_t)n_nodes * HDIM * sizeof(float) * 2;
        const int agg_blocks_ct = (int)(((long long)n_edges_ct * 32 + 255) / 256);
        const int agg_blocks_cb = (int)(((long long)n_edges_cb * 32 + 255) / 256);
        const float* hcur = h0;
        for (int layer = 0; layer < 2; ++layer) {
            hipMemsetAsync(d_ws, 0, mbytes, stream);
            edge_agg_kernel<<<agg_blocks_ct, 256, 0, stream>>>(
                hcur, feat_ct, src_ct, dst_ct, mct, n_edges_ct);
            edge_agg_kernel<<<agg_blocks_cb, 256, 0, stream>>>(
                hcur, feat_cb, src_cb, dst_cb, mcb, n_edges_cb);
            gemm_gelu_res_kernel<<<256, 256, 0, stream>>>(
                mct, mcb, layer ? W1 : W0, layer ? b1 : b0, hcur, out, n_nodes);
            hcur = out;
        }
    }
}

// Round 6
// 461.071 us; speedup vs baseline: 13.1737x; 1.1272x over previous
//
#include <hip/hip_runtime.h>
#include <math.h>

#define HDIM 128
typedef unsigned int uint;
using short8 = __attribute__((ext_vector_type(8))) short;
using f32x4  = __attribute__((ext_vector_type(4))) float;

__device__ __forceinline__ uint pack_bf16x2(float a, float b) {
    uint ua = __float_as_uint(a), ub = __float_as_uint(b);
    ua = (ua + 0x7fffu + ((ua >> 16) & 1u)) >> 16;
    ub = (ub + 0x7fffu + ((ub >> 16) & 1u)) & 0xffff0000u;
    return ua | ub;
}
__device__ __forceinline__ unsigned short pack_bf16(float a) {
    uint ua = __float_as_uint(a);
    return (unsigned short)((ua + 0x7fffu + ((ua >> 16) & 1u)) >> 16);
}

// ---- prep: h->bf16, W->Wt bf16, + histogram of both dst arrays (fused) -----
__global__ __launch_bounds__(256) void prep_kernel(
    const float* __restrict__ h, uint* __restrict__ hb, int n_pairs,
    const float* __restrict__ W0, const float* __restrict__ W1,
    unsigned short* __restrict__ Wt0, unsigned short* __restrict__ Wt1,
    const int* __restrict__ dst_ct, int* __restrict__ counts_ct, int n_ct,
    const int* __restrict__ dst_cb, int* __restrict__ counts_cb, int n_cb)
{
    const int t0 = n_pairs;
    const int t1 = t0 + 2 * 32768;
    const int t2 = t1 + n_ct;
    const int total = t2 + n_cb;
    for (int i = blockIdx.x * 256 + threadIdx.x; i < total; i += gridDim.x * 256) {
        if (i < t0) {
            float2 v = reinterpret_cast<const float2*>(h)[i];
            hb[i] = pack_bf16x2(v.x, v.y);
        } else if (i < t1) {
            int t = i - t0;
            const float* W = (t < 32768) ? W0 : W1;
            unsigned short* Wt = (t < 32768) ? Wt0 : Wt1;
            int j = t & 32767;
            int c = j >> 8, k = j & 255;
            Wt[j] = pack_bf16(W[k * HDIM + c]);
        } else if (i < t2) {
            atomicAdd(&counts_ct[dst_ct[i - t1]], 1);
        } else {
            atomicAdd(&counts_cb[dst_cb[i - t2]], 1);
        }
    }
}

__global__ __launch_bounds__(1024) void scan_kernel(
    const int* __restrict__ counts_ct, const int* __restrict__ counts_cb,
    int* __restrict__ rowptr_ct, int* __restrict__ rowptr_cb, int n)
{
    const int* counts = blockIdx.x ? counts_cb : counts_ct;
    int* rowptr       = blockIdx.x ? rowptr_cb : rowptr_ct;
    __shared__ int sums[1024];
    const int t = threadIdx.x;
    const int chunk = (n + 1023) / 1024;
    const int beg = t * chunk;
    const int end = min(n, beg + chunk);
    int s = 0;
    for (int i = beg; i < end; ++i) s += counts[i];
    sums[t] = s;
    __syncthreads();
    for (int off = 1; off < 1024; off <<= 1) {
        int v = (t >= off) ? sums[t - off] : 0;
        __syncthreads();
        sums[t] += v;
        __syncthreads();
    }
    int run = (t == 0) ? 0 : sums[t - 1];
    for (int i = beg; i < end; ++i) { rowptr[i] = run; run += counts[i]; }
    if (t == 1023) rowptr[n] = sums[1023];
}

// fill: dst-sorted packed (src, feat) int2 records; reverse-bucket via
// atomicSub on counts (counts are dead after scan -> no pos[] arrays).
__global__ __launch_bounds__(256) void fill_kernel(
    const int* __restrict__ dst_ct, const int* __restrict__ src_ct,
    const float* __restrict__ feat_ct, const int* __restrict__ rowptr_ct,
    int* __restrict__ counts_ct, int2* __restrict__ ecsr_ct, int n_ct,
    const int* __restrict__ dst_cb, const int* __restrict__ src_cb,
    const float* __restrict__ feat_cb, const int* __restrict__ rowptr_cb,
    int* __restrict__ counts_cb, int2* __restrict__ ecsr_cb, int n_cb)
{
    const int total = n_ct + n_cb;
    for (int i = blockIdx.x * 256 + threadIdx.x; i < total; i += gridDim.x * 256) {
        if (i < n_ct) {
            int d = dst_ct[i];
            int p = rowptr_ct[d] + atomicSub(&counts_ct[d], 1) - 1;
            ecsr_ct[p] = make_int2(src_ct[i], __float_as_int(feat_ct[i]));
        } else {
            int k = i - n_ct;
            int d = dst_cb[k];
            int p = rowptr_cb[d] + atomicSub(&counts_cb[d], 1) - 1;
            ecsr_cb[p] = make_int2(src_cb[k], __float_as_int(feat_cb[k]));
        }
    }
}

// ------ Gather aggregation: 2 edges/wave-step, uint2 (4 bf16) per lane ------
// half = lane>>5 picks the edge of the pair; lanes 0-31 and 32-63 each cover
// a full 256B h row. Cross-half combine once per node via shfl_xor(32).
__global__ __launch_bounds__(256) void csr_gather_bf16_kernel(
    const uint2* __restrict__ hb,
    const int* __restrict__ rp_ct, const int2* __restrict__ e_ct,
    const int* __restrict__ rp_cb, const int2* __restrict__ e_cb,
    uint2* __restrict__ mct, uint2* __restrict__ mcb, int n_nodes)
{
    const int lane = threadIdx.x & 63;
    const int half = lane >> 5;          // which edge of the pair
    const int sub  = lane & 31;          // uint2 slot within the 256B row
    const int wave = (blockIdx.x * 256 + threadIdx.x) >> 6;
    const int nwaves = (gridDim.x * 256) >> 6;
    const int total = 2 * n_nodes;
    for (int v = wave; v < total; v += nwaves) {
        const bool cbt = (v >= n_nodes);
        const int n = cbt ? (v - n_nodes) : v;
        const int* rp    = cbt ? rp_cb : rp_ct;
        const int2* ecsr = cbt ? e_cb : e_ct;
        uint2* m = cbt ? mcb : mct;
        const int beg = rp[n], end = rp[n + 1];
        float a0 = 0.f, a1 = 0.f, a2 = 0.f, a3 = 0.f;
        for (int i0 = beg; i0 < end; i0 += 64) {
            const int cnt = min(64, end - i0);
            int s = 0; float f = 0.0f;
            if (lane < cnt) {
                int2 e = ecsr[i0 + lane];
                s = e.x;
                f = __int_as_float(e.y);
            }
            const int npair = (cnt + 1) >> 1;
            #pragma unroll 4
            for (int jj = 0; jj < npair; ++jj) {
                int idx = jj * 2 + half;     // >= cnt lanes carry f=0 (safe)
                int   sj = __shfl(s, idx);
                float fj = __shfl(f, idx);
                uint2 hv = hb[(size_t)sj * 32 + sub];
                a0 = fmaf(fj, __uint_as_float(hv.x << 16),         a0);
                a1 = fmaf(fj, __uint_as_float(hv.x & 0xffff0000u), a1);
                a2 = fmaf(fj, __uint_as_float(hv.y << 16),         a2);
                a3 = fmaf(fj, __uint_as_float(hv.y & 0xffff0000u), a3);
            }
        }
        // combine the two half-wave accumulators
        a0 += __shfl_xor(a0, 32);
        a1 += __shfl_xor(a1, 32);
        a2 += __shfl_xor(a2, 32);
        a3 += __shfl_xor(a3, 32);
        if (half == 0)
            m[(size_t)n * 32 + sub] = make_uint2(pack_bf16x2(a0, a1),
                                                 pack_bf16x2(a2, a3));
    }
}

// -------- Zero-LDS MFMA GEMM: wave owns 32 rows x all 128 cols --------------
// A fragments read once per block; Wt (64KB) stays L2-hot. No LDS/barriers.
__global__ __launch_bounds__(256) void gemm_mfma_kernel(
    const unsigned short* __restrict__ mct, const unsigned short* __restrict__ mcb,
    const unsigned short* __restrict__ Wt, const float* __restrict__ bias,
    const float* __restrict__ h_in, float* __restrict__ h_out,
    unsigned short* __restrict__ hb_out, int n_nodes, int write_hb)
{
    const int base = blockIdx.x * 128;
    const int lane = threadIdx.x & 63;
    const int wid  = threadIdx.x >> 6;
    const int lr = lane & 15, lg = lane >> 4;
    const int row0 = base + wid * 32;

    f32x4 acc[2][8];
    #pragma unroll
    for (int mi = 0; mi < 2; ++mi)
        #pragma unroll
        for (int ni = 0; ni < 8; ++ni)
            acc[mi][ni] = (f32x4){0.f, 0.f, 0.f, 0.f};

    const int last = (base + 128 > n_nodes);

    #pragma unroll
    for (int ks = 0; ks < 8; ++ks) {
        const int koff = ks * 32 + lg * 8;   // 16B aligned, stays within a half
        short8 a[2], b[8];
        #pragma unroll
        for (int mi = 0; mi < 2; ++mi) {
            int node = row0 + mi * 16 + lr;
            if (last && node >= n_nodes) node = n_nodes - 1;  // clamp (dup rows OK)
            const unsigned short* srcp = (koff < 128)
                ? (mct + (size_t)node * HDIM + koff)
                : (mcb + (size_t)node * HDIM + (koff - 128));
            a[mi] = *reinterpret_cast<const short8*>(srcp);
        }
        #pragma unroll
        for (int ni = 0; ni < 8; ++ni) {
            int col = ni * 16 + lr;
            b[ni] = *reinterpret_cast<const short8*>(Wt + (size_t)col * 256 + koff);
        }
        #pragma unroll
        for (int mi = 0; mi < 2; ++mi)
            #pragma unroll
            for (int ni = 0; ni < 8; ++ni)
                acc[mi][ni] = __builtin_amdgcn_mfma_f32_16x16x32_bf16(
                    a[mi], b[ni], acc[mi][ni], 0, 0, 0);
    }

    // epilogue: C[row=(lane>>4)*4+reg][col=lane&15] per fragment
    #pragma unroll
    for (int mi = 0; mi < 2; ++mi) {
        #pragma unroll
        for (int ni = 0; ni < 8; ++ni) {
            const int col = ni * 16 + lr;
            const float bc = bias[col];
            #pragma unroll
            for (int j = 0; j < 4; ++j) {
                int node = row0 + mi * 16 + lg * 4 + j;
                if (node < n_nodes) {
                    float x = acc[mi][ni][j] + bc;
                    float g = 0.5f * x * (1.0f + erff(x * 0.70710678118654752f));
                    float o = h_in[(size_t)node * HDIM + col] + g;
                    h_out[(size_t)node * HDIM + col] = o;
                    if (write_hb)
                        hb_out[(size_t)node * HDIM + col] = pack_bf16(o);
                }
            }
        }
    }
}

// ---------------- Fallback path kernels (ws too small) ----------------------
__global__ __launch_bounds__(256) void edge_agg_kernel(
    const float* __restrict__ h, const float* __restrict__ feat,
    const int* __restrict__ src, const int* __restrict__ dst,
    float* __restrict__ m, int n_edges)
{
    long long tid = (long long)blockIdx.x * 256 + threadIdx.x;
    int e = (int)(tid >> 5);
    if (e >= n_edges) return;
    int q = (int)(tid & 31);
    float f = feat[e];
    size_t s = (size_t)src[e] * HDIM;
    size_t d = (size_t)dst[e] * HDIM;
    float4 v = reinterpret_cast<const float4*>(h + s)[q];
    float* mp = m + d + (size_t)q * 4;
    unsafeAtomicAdd(mp + 0, f * v.x);
    unsafeAtomicAdd(mp + 1, f * v.y);
    unsafeAtomicAdd(mp + 2, f * v.z);
    unsafeAtomicAdd(mp + 3, f * v.w);
}

__global__ __launch_bounds__(256) void gemm_gelu_res_kernel(
    const float* __restrict__ mct, const float* __restrict__ mcb,
    const float* __restrict__ W, const float* __restrict__ bias,
    const float* __restrict__ h_in, float* __restrict__ h_out, int n_nodes)
{
    __shared__ float Wl[256 * HDIM];
    __shared__ float trow[8][2 * HDIM];
    for (int i = threadIdx.x; i < 256 * HDIM; i += 256)
        Wl[i] = W[i];
    const int c = threadIdx.x & 127;
    const int g = threadIdx.x >> 7;
    const float bc = bias[c];
    __syncthreads();
    const int niter = (n_nodes + 7) >> 3;
    for (int it = blockIdx.x; it < niter; it += gridDim.x) {
        __syncthreads();
        for (int j = threadIdx.x; j < 8 * 256; j += 256) {
            int nn = j >> 8;
            int k  = j & 255;
            long long node = (long long)it * 8 + nn;
            float val = 0.0f;
            if (node < n_nodes)
                val = (k < HDIM) ? mct[node * HDIM + k]
                                 : mcb[node * HDIM + (k - HDIM)];
            trow[nn][k] = val;
        }
        __syncthreads();
        const float* t0 = trow[g * 4 + 0];
        const float* t1 = trow[g * 4 + 1];
        const float* t2 = trow[g * 4 + 2];
        const float* t3 = trow[g * 4 + 3];
        float a0 = bc, a1 = bc, a2 = bc, a3 = bc;
        #pragma unroll 8
        for (int k = 0; k < 256; ++k) {
            float w = Wl[k * HDIM + c];
            a0 = fmaf(t0[k], w, a0);
            a1 = fmaf(t1[k], w, a1);
            a2 = fmaf(t2[k], w, a2);
            a3 = fmaf(t3[k], w, a3);
        }
        float accs[4] = {a0, a1, a2, a3};
        #pragma unroll
        for (int j = 0; j < 4; ++j) {
            long long node = (long long)it * 8 + g * 4 + j;
            if (node < n_nodes) {
                float x = accs[j];
                float gl = 0.5f * x * (1.0f + erff(x * 0.70710678118654752f));
                h_out[node * HDIM + c] = h_in[node * HDIM + c] + gl;
            }
        }
    }
}

extern "C" void kernel_launch(void* const* d_in, const int* in_sizes, int n_in,
                              void* d_out, int out_size, void* d_ws, size_t ws_size,
                              hipStream_t stream)
{
    const float* h0      = (const float*)d_in[0];
    const float* feat_ct = (const float*)d_in[1];
    const float* feat_cb = (const float*)d_in[2];
    const int*   src_ct  = (const int*)d_in[3];
    const int*   dst_ct  = (const int*)d_in[4];
    const int*   src_cb  = (const int*)d_in[5];
    const int*   dst_cb  = (const int*)d_in[6];
    const float* W0      = (const float*)d_in[7];
    const float* b0      = (const float*)d_in[8];
    const float* W1      = (const float*)d_in[9];
    const float* b1      = (const float*)d_in[10];

    const int n_nodes    = in_sizes[0] / HDIM;
    const int n_edges_ct = in_sizes[3];
    const int n_edges_cb = in_sizes[5];
    float* out = (float*)d_out;

    // ---- workspace layout (256B-aligned chunks) ----
    char* p = (char*)d_ws;
    auto take = [&](size_t bytes) -> char* {
        char* r = p;
        p += (bytes + 255) & ~(size_t)255;
        return r;
    };
    unsigned short* hb   = (unsigned short*)take((size_t)n_nodes * HDIM * 2);
    unsigned short* mctb = (unsigned short*)take((size_t)n_nodes * HDIM * 2);
    unsigned short* mcbb = (unsigned short*)take((size_t)n_nodes * HDIM * 2);
    unsigned short* Wt0  = (unsigned short*)take(32768 * 2);
    unsigned short* Wt1  = (unsigned short*)take(32768 * 2);
    int* counts_ct = (int*)take((size_t)n_nodes * 4);
    int* counts_cb = (int*)take((size_t)n_nodes * 4);
    int* rowptr_ct = (int*)take(((size_t)n_nodes + 1) * 4);
    int* rowptr_cb = (int*)take(((size_t)n_nodes + 1) * 4);
    int2* ecsr_ct = (int2*)take((size_t)n_edges_ct * 8);
    int2* ecsr_cb = (int2*)take((size_t)n_edges_cb * 8);
    const size_t need_bytes = (size_t)(p - (char*)d_ws);

    if (ws_size >= need_bytes) {
        // zero counts (incl. alignment padding between the two arrays)
        const size_t zero_span = (size_t)((char*)(counts_cb + n_nodes) - (char*)counts_ct);
        hipMemsetAsync(counts_ct, 0, zero_span, stream);
        prep_kernel<<<2048, 256, 0, stream>>>(
            h0, (uint*)hb, n_nodes * (HDIM / 2), W0, W1, Wt0, Wt1,
            dst_ct, counts_ct, n_edges_ct, dst_cb, counts_cb, n_edges_cb);
        scan_kernel<<<2, 1024, 0, stream>>>(counts_ct, counts_cb,
                                            rowptr_ct, rowptr_cb, n_nodes);
        fill_kernel<<<1024, 256, 0, stream>>>(
            dst_ct, src_ct, feat_ct, rowptr_ct, counts_ct, ecsr_ct, n_edges_ct,
            dst_cb, src_cb, feat_cb, rowptr_cb, counts_cb, ecsr_cb, n_edges_cb);
        const int gemm_blocks = (n_nodes + 127) / 128;
        const float* hin = h0;
        for (int layer = 0; layer < 2; ++layer) {
            csr_gather_bf16_kernel<<<2048, 256, 0, stream>>>(
                (const uint2*)hb, rowptr_ct, ecsr_ct, rowptr_cb, ecsr_cb,
                (uint2*)mctb, (uint2*)mcbb, n_nodes);
            gemm_mfma_kernel<<<gemm_blocks, 256, 0, stream>>>(
                mctb, mcbb, layer ? Wt1 : Wt0, layer ? b1 : b0,
                hin, out, hb, n_nodes, layer == 0 ? 1 : 0);
            hin = out;
        }
    } else {
        // fallback: proven atomic + fp32 path
        float* mct = (float*)d_ws;
        float* mcb = mct + (size_t)n_nodes * HDIM;
        const size_t mbytes = (size_t)n_nodes * HDIM * sizeof(float) * 2;
        const int agg_blocks_ct = (int)(((long long)n_edges_ct * 32 + 255) / 256);
        const int agg_blocks_cb = (int)(((long long)n_edges_cb * 32 + 255) / 256);
        const float* hcur = h0;
        for (int layer = 0; layer < 2; ++layer) {
            hipMemsetAsync(d_ws, 0, mbytes, stream);
            edge_agg_kernel<<<agg_blocks_ct, 256, 0, stream>>>(
                hcur, feat_ct, src_ct, dst_ct, mct, n_edges_ct);
            edge_agg_kernel<<<agg_blocks_cb, 256, 0, stream>>>(
                hcur, feat_cb, src_cb, dst_cb, mcb, n_edges_cb);
            gemm_gelu_res_kernel<<<256, 256, 0, stream>>>(
                mct, mcb, layer ? W1 : W0, layer ? b1 : b0, hcur, out, n_nodes);
            hcur = out;
        }
    }
}